// Round 2
// baseline (1062.533 us; speedup 1.0000x reference)
//
#include <hip/hip_runtime.h>
#include <cstdio>
#include <cstdint>

typedef _Float16 f16;
typedef _Float16 f16x4 __attribute__((ext_vector_type(4)));
typedef _Float16 f16x8 __attribute__((ext_vector_type(8)));
typedef float f32x4 __attribute__((ext_vector_type(4)));

#define GLL16(gp, lp)                                                          \
  __builtin_amdgcn_global_load_lds(                                            \
      (const __attribute__((address_space(1))) void*)(gp),                     \
      (__attribute__((address_space(3))) void*)(lp), 16, 0, 0)

// ---------------- fp32 -> fp16 elementwise (h) ----------------
__global__ void cvt_f32_f16_kernel(const float* __restrict__ in,
                                   f16* __restrict__ out, int n4) {
  int i = blockIdx.x * blockDim.x + threadIdx.x;
  if (i < n4) {
    float4 v = reinterpret_cast<const float4*>(in)[i];
    f16x4 o;
    o[0] = (f16)v.x; o[1] = (f16)v.y; o[2] = (f16)v.z; o[3] = (f16)v.w;
    reinterpret_cast<f16x4*>(out)[i] = o;
  }
}

// ---------------- fp32 (R x C) -> fp16 transposed (C x R), 9 slots ----------
__global__ void tr_cvt_kernel(const float* __restrict__ inA,
                              const float* __restrict__ inB,
                              f16* __restrict__ out, int R, int C, int nA) {
  int slot = blockIdx.z;
  const float* src = (slot < nA) ? (inA + (size_t)slot * R * C) : inB;
  f16* dst = out + (size_t)slot * R * C;
  __shared__ float tile[32][33];
  int tx = threadIdx.x, ty = threadIdx.y;
  int c = blockIdx.x * 32 + tx;
#pragma unroll
  for (int j = 0; j < 4; ++j) {
    int r = blockIdx.y * 32 + ty + j * 8;
    tile[ty + j * 8][tx] = src[(size_t)r * C + c];
  }
  __syncthreads();
  int oc = blockIdx.y * 32 + tx;
#pragma unroll
  for (int j = 0; j < 4; ++j) {
    int orr = blockIdx.x * 32 + ty + j * 8;
    dst[(size_t)orr * R + oc] = (f16)tile[tx][ty + j * 8];
  }
}

// ---------------- fused UG GEMM: act = silu(h@Wg) * (h@Wu) * coef -----------
// BM=128 BN=128 BK=32, dual B operands, one K-loop. XCD-chunked swizzle,
// mt fastest (consecutive logical blocks share the 512KB W-stripe; h(4MB)
// stays L2-resident per XCD).
__global__ __launch_bounds__(256) void gemmUG_kernel(
    const f16* __restrict__ A, const f16* __restrict__ Bg,
    const f16* __restrict__ Bu, f16* __restrict__ T,
    const float* __restrict__ gate, const float* __restrict__ sgp) {
  const int NWG = 32 * 16 * 9;
  int bid = blockIdx.x;
  int wg = (bid & 7) * (NWG / 8) + (bid >> 3);
  int mt = wg & 15;
  int nt = (wg >> 4) & 31;
  int slot = wg >> 9;

  __shared__ __align__(16) f16 As[4096];   // [128 m][32 k]
  __shared__ __align__(16) f16 Bgs[4096];  // [128 n][32 k]
  __shared__ __align__(16) f16 Bus[4096];
  int t = threadIdx.x, w = t >> 6, l = t & 63;

  const f16* Bgb = Bg + (size_t)slot * (4096ull * 1024);
  const f16* Bub = Bu + (size_t)slot * (4096ull * 1024);

  const f16* gA0 = A + (size_t)(mt * 128 + w * 16 + (l >> 2)) * 1024 + (l & 3) * 8;
  const f16* gA1 = gA0 + (size_t)64 * 1024;
  const f16* gG0 = Bgb + (size_t)(nt * 128 + w * 16 + (l >> 2)) * 1024 + (l & 3) * 8;
  const f16* gG1 = gG0 + (size_t)64 * 1024;
  const f16* gU0 = Bub + (size_t)(nt * 128 + w * 16 + (l >> 2)) * 1024 + (l & 3) * 8;
  const f16* gU1 = gU0 + (size_t)64 * 1024;
  f16* lA0 = &As[w * 512];
  f16* lA1 = &As[2048 + w * 512];
  f16* lG0 = &Bgs[w * 512];
  f16* lG1 = &Bgs[2048 + w * 512];
  f16* lU0 = &Bus[w * 512];
  f16* lU1 = &Bus[2048 + w * 512];

  int wr = w >> 1, wc = w & 1;
  int lrow = l & 15, lkb = (l >> 4) * 8;

  f32x4 accg[4][4] = {};
  f32x4 accu[4][4] = {};

  for (int kt = 0; kt < 32; ++kt) {
    if (kt) __syncthreads();
    int ko = kt * 32;
    GLL16(gA0 + ko, lA0);
    GLL16(gA1 + ko, lA1);
    GLL16(gG0 + ko, lG0);
    GLL16(gG1 + ko, lG1);
    GLL16(gU0 + ko, lU0);
    GLL16(gU1 + ko, lU1);
    __syncthreads();

    f16x8 aF[4], gF[4], uF[4];
#pragma unroll
    for (int mi = 0; mi < 4; ++mi)
      aF[mi] = *reinterpret_cast<const f16x8*>(
          &As[(wr * 64 + mi * 16 + lrow) * 32 + lkb]);
#pragma unroll
    for (int ni = 0; ni < 4; ++ni) {
      gF[ni] = *reinterpret_cast<const f16x8*>(
          &Bgs[(wc * 64 + ni * 16 + lrow) * 32 + lkb]);
      uF[ni] = *reinterpret_cast<const f16x8*>(
          &Bus[(wc * 64 + ni * 16 + lrow) * 32 + lkb]);
    }
#pragma unroll
    for (int mi = 0; mi < 4; ++mi)
#pragma unroll
      for (int ni = 0; ni < 4; ++ni) {
        accg[mi][ni] = __builtin_amdgcn_mfma_f32_16x16x32_f16(
            aF[mi], gF[ni], accg[mi][ni], 0, 0, 0);
        accu[mi][ni] = __builtin_amdgcn_mfma_f32_16x16x32_f16(
            aF[mi], uF[ni], accu[mi][ni], 0, 0, 0);
      }
  }

  // epilogue: col = lane&15, row = (lane>>4)*4 + j
  int r0 = (l >> 4) * 4, c0 = l & 15;
  int b = (mt * 128) >> 10;
  float s = sgp[b];
  float coef = (slot < 8) ? (1.f - s) * gate[b * 8 + slot] : s;
#pragma unroll
  for (int mi = 0; mi < 4; ++mi) {
#pragma unroll
    for (int ni = 0; ni < 4; ++ni) {
#pragma unroll
      for (int j = 0; j < 4; ++j) {
        int grow = mt * 128 + wr * 64 + mi * 16 + r0 + j;
        int gcol = nt * 128 + wc * 64 + ni * 16 + c0;
        float g = accg[mi][ni][j];
        float u = accu[mi][ni][j];
        float sil = g / (1.f + __expf(-g));
        T[(size_t)grow * 36864 + slot * 4096 + gcol] = (f16)(sil * u * coef);
      }
    }
  }
}

// ---------------- down-proj: P[slot] = T[:,slot] @ WdT[slot]^T --------------
// BM=128 BN=128 BK=32, K=4096. XCD-chunked swizzle, nt fastest (8 consecutive
// logical blocks share each 1MB T row-panel -> T fetched ~once from HBM).
__global__ __launch_bounds__(256) void gemmD_kernel(
    const f16* __restrict__ A, const f16* __restrict__ Bt,
    float* __restrict__ P) {
  const int NWG = 8 * 16 * 9;
  int bid = blockIdx.x;
  int wg = (bid & 7) * (NWG / 8) + (bid >> 3);
  int nt = wg & 7;
  int mt = (wg >> 3) & 15;
  int slot = wg >> 7;

  __shared__ __align__(16) f16 As[4096];
  __shared__ __align__(16) f16 Bs[4096];
  int t = threadIdx.x, w = t >> 6, l = t & 63;

  const f16* Ab = A + (size_t)slot * 4096;          // column block of T
  const f16* Bb = Bt + (size_t)slot * (4096ull * 1024);

  const f16* gA0 = Ab + (size_t)(mt * 128 + w * 16 + (l >> 2)) * 36864 + (l & 3) * 8;
  const f16* gA1 = gA0 + (size_t)64 * 36864;
  const f16* gB0 = Bb + (size_t)(nt * 128 + w * 16 + (l >> 2)) * 4096 + (l & 3) * 8;
  const f16* gB1 = gB0 + (size_t)64 * 4096;
  f16* lA0 = &As[w * 512];
  f16* lA1 = &As[2048 + w * 512];
  f16* lB0 = &Bs[w * 512];
  f16* lB1 = &Bs[2048 + w * 512];

  int wr = w >> 1, wc = w & 1;
  int lrow = l & 15, lkb = (l >> 4) * 8;

  f32x4 acc[4][4] = {};

  for (int kt = 0; kt < 128; ++kt) {
    if (kt) __syncthreads();
    int ko = kt * 32;
    GLL16(gA0 + ko, lA0);
    GLL16(gA1 + ko, lA1);
    GLL16(gB0 + ko, lB0);
    GLL16(gB1 + ko, lB1);
    __syncthreads();

    f16x8 aF[4], bF[4];
#pragma unroll
    for (int mi = 0; mi < 4; ++mi)
      aF[mi] = *reinterpret_cast<const f16x8*>(
          &As[(wr * 64 + mi * 16 + lrow) * 32 + lkb]);
#pragma unroll
    for (int ni = 0; ni < 4; ++ni)
      bF[ni] = *reinterpret_cast<const f16x8*>(
          &Bs[(wc * 64 + ni * 16 + lrow) * 32 + lkb]);
#pragma unroll
    for (int mi = 0; mi < 4; ++mi)
#pragma unroll
      for (int ni = 0; ni < 4; ++ni)
        acc[mi][ni] = __builtin_amdgcn_mfma_f32_16x16x32_f16(
            aF[mi], bF[ni], acc[mi][ni], 0, 0, 0);
  }

  int r0 = (l >> 4) * 4, c0 = l & 15;
#pragma unroll
  for (int mi = 0; mi < 4; ++mi) {
#pragma unroll
    for (int ni = 0; ni < 4; ++ni) {
#pragma unroll
      for (int j = 0; j < 4; ++j) {
        int grow = mt * 128 + wr * 64 + mi * 16 + r0 + j;
        int gcol = nt * 128 + wc * 64 + ni * 16 + c0;
        P[((size_t)slot << 21) + (size_t)grow * 1024 + gcol] = acc[mi][ni][j];
      }
    }
  }
}

// ---------------- sum 9 split-K partials -> fp32 out ------------------------
__global__ void reduce9_kernel(const float* __restrict__ P,
                               float* __restrict__ out, int n4) {
  int i = blockIdx.x * blockDim.x + threadIdx.x;
  if (i < n4) {
    float4 s = {0.f, 0.f, 0.f, 0.f};
#pragma unroll
    for (int e = 0; e < 9; ++e) {
      float4 v = reinterpret_cast<const float4*>(P + ((size_t)e << 21))[i];
      s.x += v.x; s.y += v.y; s.z += v.z; s.w += v.w;
    }
    reinterpret_cast<float4*>(out)[i] = s;
  }
}

extern "C" void kernel_launch(void* const* d_in, const int* in_sizes, int n_in,
                              void* d_out, int out_size, void* d_ws,
                              size_t ws_size, hipStream_t stream) {
  const float* h    = (const float*)d_in[0];
  const float* gate = (const float*)d_in[1];
  const float* sgp  = (const float*)d_in[2];
  const float* Wg   = (const float*)d_in[3];
  const float* Wu   = (const float*)d_in[4];
  const float* Wd   = (const float*)d_in[5];
  const float* Sg   = (const float*)d_in[6];
  const float* Su   = (const float*)d_in[7];
  const float* Sd   = (const float*)d_in[8];

  const size_t SZ_HB = 4194304;      // 2048*1024 f16
  const size_t SZ_W  = 75497472;     // 9*4096*1024 f16
  const size_t SZ_T  = 150994944;    // 2048*36864 f16
  const size_t SZ_P  = 75497472;     // 9*2048*1024 f32
  char* ws = (char*)d_ws;
  f16*   hb  = (f16*)(ws);
  f16*   WgT = (f16*)(ws + SZ_HB);
  f16*   WuT = (f16*)(ws + SZ_HB + SZ_W);
  f16*   WdT = (f16*)(ws + SZ_HB + 2 * SZ_W);
  f16*   T   = (f16*)(ws + SZ_HB + 3 * SZ_W);
  float* P   = (float*)(ws + SZ_HB + 3 * SZ_W + SZ_T);
  size_t need = SZ_HB + 3 * SZ_W + SZ_T + SZ_P;
  if (ws_size < need) {
    fprintf(stderr, "kernel_launch: ws too small (%zu < %zu)\n", ws_size, need);
    return;
  }
  float* out = (float*)d_out;

  cvt_f32_f16_kernel<<<2048, 256, 0, stream>>>(h, hb, 524288);
  tr_cvt_kernel<<<dim3(128, 32, 9), dim3(32, 8), 0, stream>>>(Wg, Sg, WgT, 1024, 4096, 8);
  tr_cvt_kernel<<<dim3(128, 32, 9), dim3(32, 8), 0, stream>>>(Wu, Su, WuT, 1024, 4096, 8);
  tr_cvt_kernel<<<dim3(32, 128, 9), dim3(32, 8), 0, stream>>>(Wd, Sd, WdT, 4096, 1024, 8);

  gemmUG_kernel<<<4608, 256, 0, stream>>>(hb, WgT, WuT, T, gate, sgp);
  gemmD_kernel<<<1152, 256, 0, stream>>>(T, WdT, P);
  reduce9_kernel<<<2048, 256, 0, stream>>>(P, out, 524288);
}

// Round 3
// 757.636 us; speedup vs baseline: 1.4024x; 1.4024x over previous
//
#include <hip/hip_runtime.h>
#include <cstdio>
#include <cstdint>

typedef _Float16 f16;
typedef _Float16 f16x4 __attribute__((ext_vector_type(4)));
typedef _Float16 f16x8 __attribute__((ext_vector_type(8)));
typedef float f32x4 __attribute__((ext_vector_type(4)));

#define GLL16(gp, lp)                                                          \
  __builtin_amdgcn_global_load_lds(                                            \
      (const __attribute__((address_space(1))) void*)(gp),                     \
      (__attribute__((address_space(3))) void*)(lp), 16, 0, 0)

// ---------------- fp32 -> fp16 elementwise (h) ----------------
__global__ void cvt_f32_f16_kernel(const float* __restrict__ in,
                                   f16* __restrict__ out, int n4) {
  int i = blockIdx.x * blockDim.x + threadIdx.x;
  if (i < n4) {
    float4 v = reinterpret_cast<const float4*>(in)[i];
    f16x4 o;
    o[0] = (f16)v.x; o[1] = (f16)v.y; o[2] = (f16)v.z; o[3] = (f16)v.w;
    reinterpret_cast<f16x4*>(out)[i] = o;
  }
}

// ---------------- fp32 (R x C) -> fp16 transposed (C x R), 9 slots ----------
__global__ void tr_cvt_kernel(const float* __restrict__ inA,
                              const float* __restrict__ inB,
                              f16* __restrict__ out, int R, int C, int nA) {
  int slot = blockIdx.z;
  const float* src = (slot < nA) ? (inA + (size_t)slot * R * C) : inB;
  f16* dst = out + (size_t)slot * R * C;
  __shared__ float tile[32][33];
  int tx = threadIdx.x, ty = threadIdx.y;
  int c = blockIdx.x * 32 + tx;
#pragma unroll
  for (int j = 0; j < 4; ++j) {
    int r = blockIdx.y * 32 + ty + j * 8;
    tile[ty + j * 8][tx] = src[(size_t)r * C + c];
  }
  __syncthreads();
  int oc = blockIdx.y * 32 + tx;
#pragma unroll
  for (int j = 0; j < 4; ++j) {
    int orr = blockIdx.x * 32 + ty + j * 8;
    dst[(size_t)orr * R + oc] = (f16)tile[tx][ty + j * 8];
  }
}

// =================== 256x256 8-phase GEMM (T2+T3+T4+T5) =====================
// C[m][n] = sum_k A[m][k]*Bt[n][k], M=2048 N=4096(x9 slots) K=1024.
// 512 thr / 8 waves (2Mx4N), BK=64, LDS 128KB (2 dbuf x {A,B} x 2 half-tiles
// of [128][64] f16). G4 swizzle: elem col ^= (row&7)*8, applied on the global
// SOURCE during global_load_lds staging and on ds_read addresses (rule #21).
// MODE 0: T[idx] = C ;  MODE 1: T[idx] = silu(C)*T[idx]*coef
#define BARX __builtin_amdgcn_s_barrier()
#define WAITV4 { asm volatile("s_waitcnt vmcnt(4)" ::: "memory"); __builtin_amdgcn_sched_barrier(0); }
#define WAITV0 { asm volatile("s_waitcnt vmcnt(0)" ::: "memory"); __builtin_amdgcn_sched_barrier(0); }
#define WAITL0 { asm volatile("s_waitcnt lgkmcnt(0)" ::: "memory"); __builtin_amdgcn_sched_barrier(0); }

// stage half-tile hf of K-tile (tile) for A or B: 2 x GLL16 per thread-block
#define STAGE_A(tile, hf)                                                      \
  do {                                                                         \
    const f16* g_ = Abase + (size_t)((hf) * 128) * 1024 + (tile) * 64 + aVoff; \
    f16* d_ = &lds[(2 * ((tile) & 1) + (hf)) * 8192 + w * 512];                \
    GLL16(g_, d_);                                                             \
    GLL16(g_ + 64 * 1024, d_ + 4096);                                          \
  } while (0)
#define STAGE_B(tile, hf)                                                      \
  do {                                                                         \
    const f16* g_ = Bbase + (size_t)((hf) * 128) * 1024 + (tile) * 64 + bVoff; \
    f16* d_ = &lds[32768 + (2 * ((tile) & 1) + (hf)) * 8192 + w * 512];        \
    GLL16(g_, d_);                                                             \
    GLL16(g_ + 64 * 1024, d_ + 4096);                                          \
  } while (0)

// register-subtile reads (swizzled)
#define RD_A(rh, buf)                                                          \
  do {                                                                         \
    const f16* p_ = &lds[(2 * (buf) + wr) * 8192 + (rh) * 4096];               \
    aF[0][0] = *(const f16x8*)(p_ + 0 * 1024 + vR0);                           \
    aF[0][1] = *(const f16x8*)(p_ + 0 * 1024 + vR1);                           \
    aF[1][0] = *(const f16x8*)(p_ + 1 * 1024 + vR0);                           \
    aF[1][1] = *(const f16x8*)(p_ + 1 * 1024 + vR1);                           \
    aF[2][0] = *(const f16x8*)(p_ + 2 * 1024 + vR0);                           \
    aF[2][1] = *(const f16x8*)(p_ + 2 * 1024 + vR1);                           \
    aF[3][0] = *(const f16x8*)(p_ + 3 * 1024 + vR0);                           \
    aF[3][1] = *(const f16x8*)(p_ + 3 * 1024 + vR1);                           \
  } while (0)
#define RD_B(ch, buf)                                                          \
  do {                                                                         \
    const f16* p_ = &lds[32768 + (2 * (buf) + bh) * 8192 + bq * 4096 +         \
                         (ch) * 2 * 1024];                                     \
    bF[(ch) * 2][0] = *(const f16x8*)(p_ + vR0);                               \
    bF[(ch) * 2][1] = *(const f16x8*)(p_ + vR1);                               \
    bF[(ch) * 2 + 1][0] = *(const f16x8*)(p_ + 1024 + vR0);                    \
    bF[(ch) * 2 + 1][1] = *(const f16x8*)(p_ + 1024 + vR1);                    \
  } while (0)

#define MFMA16(rh, ch)                                                         \
  do {                                                                         \
    __builtin_amdgcn_s_setprio(1);                                             \
    _Pragma("unroll") for (int rt = 0; rt < 4; ++rt)                           \
        _Pragma("unroll") for (int ct = 0; ct < 2; ++ct)                       \
        _Pragma("unroll") for (int ks = 0; ks < 2; ++ks)                       \
            acc[(rh) * 4 + rt][(ch) * 2 + ct] =                                \
        __builtin_amdgcn_mfma_f32_16x16x32_f16(                                \
            aF[rt][ks], bF[(ch) * 2 + ct][ks], acc[(rh) * 4 + rt][(ch) * 2 + ct], \
            0, 0, 0);                                                          \
    __builtin_amdgcn_s_setprio(0);                                             \
    __builtin_amdgcn_sched_barrier(0);                                         \
  } while (0)

template <int MODE>
__global__ __launch_bounds__(512, 2) void gemm256_kernel(
    const f16* __restrict__ A, const f16* __restrict__ B, f16* __restrict__ T,
    const float* __restrict__ gate, const float* __restrict__ sgp) {
  __shared__ __align__(16) f16 lds[65536];  // 128 KiB

  // grid: 1152 blocks; XCD-bijective: mt = XCD id (h-panel L2-resident)
  int wg = ((blockIdx.x & 7) * 144) + (blockIdx.x >> 3);
  int mt = wg / 144;            // 0..7
  int r144 = wg % 144;
  int slot = r144 >> 4;         // 0..8
  int nt = r144 & 15;           // 0..15

  int t = threadIdx.x, w = t >> 6, l = t & 63;
  int wr = w >> 2, wc = w & 3;  // wave grid 2M x 4N
  int bh = wc >> 1, bq = wc & 1;

  // staging source offsets (pre-swizzled: slot16 ^= row&7)
  int scol = (((l & 7) ^ ((l >> 3) & 7)) * 8);
  size_t stRow = (size_t)(w * 8 + (l >> 3)) * 1024;
  size_t aVoff = stRow + scol;
  size_t bVoff = stRow + scol;
  const f16* Abase = A + (size_t)mt * 256 * 1024;
  const f16* Bbase = B + (size_t)slot * 4096 * 1024 + (size_t)nt * 256 * 1024;

  // swizzled ds_read offsets (elem): row=(l&15), kcol = ks*32+(l>>4)*8
  int vR0 = (l & 15) * 64 + (((l >> 4) * 8) ^ ((l & 7) * 8));
  int vR1 = (l & 15) * 64 + ((32 + (l >> 4) * 8) ^ ((l & 7) * 8));

  f16x8 aF[4][2], bF[4][2];
  f32x4 acc[8][4] = {};

  // ---- prologue: B(0),A(0),B(1); wait tile0; barrier
  STAGE_B(0, 0); STAGE_B(0, 1);
  STAGE_A(0, 0); STAGE_A(0, 1);
  STAGE_B(1, 0); STAGE_B(1, 1);
  WAITV4;
  BARX;

#pragma unroll 1
  for (int it = 0; it < 7; ++it) {
    int t1 = 2 * it + 1, t2 = 2 * it + 2, t3 = 2 * it + 3;
    // p1: compute b0 (rh0,ch0); stage A0(t1)->b1
    RD_A(0, 0); RD_B(0, 0); STAGE_A(t1, 0);
    BARX; WAITL0; MFMA16(0, 0); BARX;
    // p2: (rh0,ch1); stage A1(t1)->b1
    RD_B(1, 0); STAGE_A(t1, 1);
    BARX; WAITL0; MFMA16(0, 1); BARX;
    // p3: (rh1,ch0); stage B0(t2)->b0  (b0.B reads ended p2)
    RD_A(1, 0); STAGE_B(t2, 0);
    BARX; WAITL0; MFMA16(1, 0); BARX;
    // p4: (rh1,ch1); stage B1(t2)->b0; vmcnt(4) -> tile t1 landed
    STAGE_B(t2, 1);
    BARX; MFMA16(1, 1); WAITV4; BARX;
    // p5: compute b1 (rh0,ch0); stage A0(t2)->b0 (b0.A reads ended p3)
    RD_A(0, 1); RD_B(0, 1); STAGE_A(t2, 0);
    BARX; WAITL0; MFMA16(0, 0); BARX;
    // p6: (rh0,ch1); stage A1(t2)->b0
    RD_B(1, 1); STAGE_A(t2, 1);
    BARX; WAITL0; MFMA16(0, 1); BARX;
    // p7: (rh1,ch0); stage B0(t3)->b1 (b1.B reads ended p6)
    RD_A(1, 1); STAGE_B(t3, 0);
    BARX; WAITL0; MFMA16(1, 0); BARX;
    // p8: (rh1,ch1); stage B1(t3)->b1; vmcnt(4) -> tile t2 landed
    STAGE_B(t3, 1);
    BARX; MFMA16(1, 1); WAITV4; BARX;
  }
  // ---- peeled last iteration: tiles 14 (b0), 15 (b1); no overrun stages
  RD_A(0, 0); RD_B(0, 0); STAGE_A(15, 0);
  BARX; WAITL0; MFMA16(0, 0); BARX;
  RD_B(1, 0); STAGE_A(15, 1);
  BARX; WAITL0; MFMA16(0, 1); BARX;
  RD_A(1, 0);
  BARX; WAITL0; MFMA16(1, 0); BARX;
  BARX; MFMA16(1, 1); WAITV0; BARX;
  RD_A(0, 1); RD_B(0, 1);
  BARX; WAITL0; MFMA16(0, 0); BARX;
  RD_B(1, 1);
  BARX; WAITL0; MFMA16(0, 1); BARX;
  RD_A(1, 1);
  BARX; WAITL0; MFMA16(1, 0); BARX;
  MFMA16(1, 1);

  // ---- epilogue: C/D layout col=lane&15, row=(lane>>4)*4+j
  int r0 = (l >> 4) * 4, c0 = l & 15;
  int rowbase = mt * 256 + wr * 128;
  size_t colbase = (size_t)slot * 4096 + nt * 256 + wc * 64;
  float coef = 0.f;
  if (MODE == 1) {
    int b = mt >> 2;
    float s = sgp[b];
    coef = (slot < 8) ? (1.f - s) * gate[b * 8 + slot] : s;
  }
#pragma unroll
  for (int rt = 0; rt < 8; ++rt) {
#pragma unroll
    for (int ct = 0; ct < 4; ++ct) {
#pragma unroll
      for (int j = 0; j < 4; ++j) {
        size_t idx = (size_t)(rowbase + rt * 16 + r0 + j) * 36864 + colbase +
                     ct * 16 + c0;
        float v = acc[rt][ct][j];
        if (MODE == 0) {
          T[idx] = (f16)v;
        } else {
          float u = (float)T[idx];
          T[idx] = (f16)(v / (1.f + __expf(-v)) * u * coef);
        }
      }
    }
  }
}

// ---------------- down-proj (R2 kernel, kept): P[slot] = T[:,slot] @ WdT ----
__global__ __launch_bounds__(256) void gemmD_kernel(
    const f16* __restrict__ A, const f16* __restrict__ Bt,
    float* __restrict__ P) {
  const int NWG = 8 * 16 * 9;
  int bid = blockIdx.x;
  int wg = (bid & 7) * (NWG / 8) + (bid >> 3);
  int nt = wg & 7;
  int mt = (wg >> 3) & 15;
  int slot = wg >> 7;

  __shared__ __align__(16) f16 As[4096];
  __shared__ __align__(16) f16 Bs[4096];
  int t = threadIdx.x, w = t >> 6, l = t & 63;

  const f16* Ab = A + (size_t)slot * 4096;
  const f16* Bb = Bt + (size_t)slot * (4096ull * 1024);

  const f16* gA0 = Ab + (size_t)(mt * 128 + w * 16 + (l >> 2)) * 36864 + (l & 3) * 8;
  const f16* gA1 = gA0 + (size_t)64 * 36864;
  const f16* gB0 = Bb + (size_t)(nt * 128 + w * 16 + (l >> 2)) * 4096 + (l & 3) * 8;
  const f16* gB1 = gB0 + (size_t)64 * 4096;
  f16* lA0 = &As[w * 512];
  f16* lA1 = &As[2048 + w * 512];
  f16* lB0 = &Bs[w * 512];
  f16* lB1 = &Bs[2048 + w * 512];

  int wr = w >> 1, wc = w & 1;
  int lrow = l & 15, lkb = (l >> 4) * 8;

  f32x4 acc[4][4] = {};

  for (int kt = 0; kt < 128; ++kt) {
    if (kt) __syncthreads();
    int ko = kt * 32;
    GLL16(gA0 + ko, lA0);
    GLL16(gA1 + ko, lA1);
    GLL16(gB0 + ko, lB0);
    GLL16(gB1 + ko, lB1);
    __syncthreads();

    f16x8 aF[4], bF[4];
#pragma unroll
    for (int mi = 0; mi < 4; ++mi)
      aF[mi] = *reinterpret_cast<const f16x8*>(
          &As[(wr * 64 + mi * 16 + lrow) * 32 + lkb]);
#pragma unroll
    for (int ni = 0; ni < 4; ++ni)
      bF[ni] = *reinterpret_cast<const f16x8*>(
          &Bs[(wc * 64 + ni * 16 + lrow) * 32 + lkb]);
#pragma unroll
    for (int mi = 0; mi < 4; ++mi)
#pragma unroll
      for (int ni = 0; ni < 4; ++ni)
        acc[mi][ni] = __builtin_amdgcn_mfma_f32_16x16x32_f16(
            aF[mi], bF[ni], acc[mi][ni], 0, 0, 0);
  }

  int r0 = (l >> 4) * 4, c0 = l & 15;
#pragma unroll
  for (int mi = 0; mi < 4; ++mi) {
#pragma unroll
    for (int ni = 0; ni < 4; ++ni) {
#pragma unroll
      for (int j = 0; j < 4; ++j) {
        int grow = mt * 128 + wr * 64 + mi * 16 + r0 + j;
        int gcol = nt * 128 + wc * 64 + ni * 16 + c0;
        P[((size_t)slot << 21) + (size_t)grow * 1024 + gcol] = acc[mi][ni][j];
      }
    }
  }
}

// ---------------- sum 9 split-K partials -> fp32 out ------------------------
__global__ void reduce9_kernel(const float* __restrict__ P,
                               float* __restrict__ out, int n4) {
  int i = blockIdx.x * blockDim.x + threadIdx.x;
  if (i < n4) {
    float4 s = {0.f, 0.f, 0.f, 0.f};
#pragma unroll
    for (int e = 0; e < 9; ++e) {
      float4 v = reinterpret_cast<const float4*>(P + ((size_t)e << 21))[i];
      s.x += v.x; s.y += v.y; s.z += v.z; s.w += v.w;
    }
    reinterpret_cast<float4*>(out)[i] = s;
  }
}

extern "C" void kernel_launch(void* const* d_in, const int* in_sizes, int n_in,
                              void* d_out, int out_size, void* d_ws,
                              size_t ws_size, hipStream_t stream) {
  const float* h    = (const float*)d_in[0];
  const float* gate = (const float*)d_in[1];
  const float* sgp  = (const float*)d_in[2];
  const float* Wg   = (const float*)d_in[3];
  const float* Wu   = (const float*)d_in[4];
  const float* Wd   = (const float*)d_in[5];
  const float* Sg   = (const float*)d_in[6];
  const float* Su   = (const float*)d_in[7];
  const float* Sd   = (const float*)d_in[8];

  const size_t SZ_HB = 4194304;      // 2048*1024 f16
  const size_t SZ_W  = 75497472;     // 9*4096*1024 f16
  const size_t SZ_T  = 150994944;    // 2048*36864 f16
  const size_t SZ_P  = 75497472;     // 9*2048*1024 f32
  char* ws = (char*)d_ws;
  f16*   hb  = (f16*)(ws);
  f16*   WgT = (f16*)(ws + SZ_HB);
  f16*   WuT = (f16*)(ws + SZ_HB + SZ_W);
  f16*   WdT = (f16*)(ws + SZ_HB + 2 * SZ_W);
  f16*   T   = (f16*)(ws + SZ_HB + 3 * SZ_W);
  float* P   = (float*)(ws + SZ_HB + 3 * SZ_W + SZ_T);
  size_t need = SZ_HB + 3 * SZ_W + SZ_T + SZ_P;
  if (ws_size < need) {
    fprintf(stderr, "kernel_launch: ws too small (%zu < %zu)\n", ws_size, need);
    return;
  }
  float* out = (float*)d_out;

  cvt_f32_f16_kernel<<<2048, 256, 0, stream>>>(h, hb, 524288);
  tr_cvt_kernel<<<dim3(128, 32, 9), dim3(32, 8), 0, stream>>>(Wg, Sg, WgT, 1024, 4096, 8);
  tr_cvt_kernel<<<dim3(128, 32, 9), dim3(32, 8), 0, stream>>>(Wu, Su, WuT, 1024, 4096, 8);
  tr_cvt_kernel<<<dim3(32, 128, 9), dim3(32, 8), 0, stream>>>(Wd, Sd, WdT, 4096, 1024, 8);

  gemm256_kernel<0><<<1152, 512, 0, stream>>>(hb, WuT, T, nullptr, nullptr);
  gemm256_kernel<1><<<1152, 512, 0, stream>>>(hb, WgT, T, gate, sgp);
  gemmD_kernel<<<1152, 256, 0, stream>>>(T, WdT, P);
  reduce9_kernel<<<2048, 256, 0, stream>>>(P, out, 524288);
}

// Round 4
// 651.571 us; speedup vs baseline: 1.6307x; 1.1628x over previous
//
#include <hip/hip_runtime.h>
#include <cstdio>
#include <cstdint>

typedef _Float16 f16;
typedef _Float16 f16x4 __attribute__((ext_vector_type(4)));
typedef _Float16 f16x8 __attribute__((ext_vector_type(8)));
typedef float f32x4 __attribute__((ext_vector_type(4)));

#define GLL16(gp, lp)                                                          \
  __builtin_amdgcn_global_load_lds(                                            \
      (const __attribute__((address_space(1))) void*)(gp),                     \
      (__attribute__((address_space(3))) void*)(lp), 16, 0, 0)

// ---------------- fp32 -> fp16 elementwise (h) ----------------
__global__ void cvt_f32_f16_kernel(const float* __restrict__ in,
                                   f16* __restrict__ out, int n4) {
  int i = blockIdx.x * blockDim.x + threadIdx.x;
  if (i < n4) {
    f32x4 v = reinterpret_cast<const f32x4*>(in)[i];
    f16x4 o;
    o[0] = (f16)v[0]; o[1] = (f16)v[1]; o[2] = (f16)v[2]; o[3] = (f16)v[3];
    reinterpret_cast<f16x4*>(out)[i] = o;
  }
}

// ------- fp32 [R][C] -> fp16 transposed, 64x64 tiles, coalesced stores ------
// dst[(c)*OS + r] = (f16)src[r][c]; per-slot: src slab (slot<nA: inA) else inB,
// dst slab offset slotOff. LDS XOR-swizzle: elem (c,r) at tl[c][r ^ (c&7)*8].
__global__ void tr_cvt2_kernel(const float* __restrict__ inA,
                               const float* __restrict__ inB,
                               f16* __restrict__ out, size_t slotOff,
                               int C, size_t OS, int nA) {
  int slot = blockIdx.z;
  const float* src = (slot < nA) ? inA + (size_t)slot * 64 * gridDim.y * C : inB;
  f16* dst = out + (size_t)slot * slotOff;
  __shared__ f16 tl[4096];
  int t = threadIdx.x;
  int r0 = blockIdx.y * 64, c0 = blockIdx.x * 64;
  int br = (t >> 4) * 4, bc = (t & 15) * 4;
  f32x4 v[4];
#pragma unroll
  for (int i = 0; i < 4; ++i)
    v[i] = *(const f32x4*)&src[(size_t)(r0 + br + i) * C + c0 + bc];
#pragma unroll
  for (int cc = 0; cc < 4; ++cc) {
    int c = bc + cc;
    f16x4 o;
    o[0] = (f16)v[0][cc]; o[1] = (f16)v[1][cc];
    o[2] = (f16)v[2][cc]; o[3] = (f16)v[3][cc];
    *(f16x4*)&tl[c * 64 + (br ^ ((c & 7) * 8))] = o;
  }
  __syncthreads();
  int rw = (t & 7) * 8, cw = t >> 3;
#pragma unroll
  for (int j = 0; j < 2; ++j) {
    int c = cw + j * 32;
    f16x8 o = *(const f16x8*)&tl[c * 64 + (rw ^ ((c & 7) * 8))];
    *(f16x8*)&dst[(size_t)(c0 + c) * OS + r0 + rw] = o;
  }
}

// =================== 256x256 8-phase GEMM (T2+T3+T4+T5) =====================
// MODE 0: T[idx]=C      (U pass, M=2048 N=4096x9 K=1024, LD=1024)
// MODE 1: T[idx]=silu(C)*T[idx]*coef                      (G pass)
// MODE 2: P[kpart]=C    (mega down-proj, M=2048 N=1024 K=36864 split-K=8)
#define BARX __builtin_amdgcn_s_barrier()
#define WAITV4 { asm volatile("s_waitcnt vmcnt(4)" ::: "memory"); __builtin_amdgcn_sched_barrier(0); }
#define WAITV0 { asm volatile("s_waitcnt vmcnt(0)" ::: "memory"); __builtin_amdgcn_sched_barrier(0); }
#define WAITL0 { asm volatile("s_waitcnt lgkmcnt(0)" ::: "memory"); __builtin_amdgcn_sched_barrier(0); }

#define STAGE_A(tile, hf)                                                      \
  do {                                                                         \
    const f16* g_ = Abase + (size_t)((hf) * 128) * LD + (tile) * 64 + aVoff;   \
    f16* d_ = &lds[(2 * ((tile) & 1) + (hf)) * 8192 + w * 512];                \
    GLL16(g_, d_);                                                             \
    GLL16(g_ + (size_t)64 * LD, d_ + 4096);                                    \
  } while (0)
#define STAGE_B(tile, hf)                                                      \
  do {                                                                         \
    const f16* g_ = Bbase + (size_t)((hf) * 128) * LD + (tile) * 64 + aVoff;   \
    f16* d_ = &lds[32768 + (2 * ((tile) & 1) + (hf)) * 8192 + w * 512];        \
    GLL16(g_, d_);                                                             \
    GLL16(g_ + (size_t)64 * LD, d_ + 4096);                                    \
  } while (0)

#define RD_A(rh, buf)                                                          \
  do {                                                                         \
    const f16* p_ = &lds[(2 * (buf) + wr) * 8192 + (rh) * 4096];               \
    aF[0][0] = *(const f16x8*)(p_ + 0 * 1024 + vR0);                           \
    aF[0][1] = *(const f16x8*)(p_ + 0 * 1024 + vR1);                           \
    aF[1][0] = *(const f16x8*)(p_ + 1 * 1024 + vR0);                           \
    aF[1][1] = *(const f16x8*)(p_ + 1 * 1024 + vR1);                           \
    aF[2][0] = *(const f16x8*)(p_ + 2 * 1024 + vR0);                           \
    aF[2][1] = *(const f16x8*)(p_ + 2 * 1024 + vR1);                           \
    aF[3][0] = *(const f16x8*)(p_ + 3 * 1024 + vR0);                           \
    aF[3][1] = *(const f16x8*)(p_ + 3 * 1024 + vR1);                           \
  } while (0)
#define RD_B(ch, buf)                                                          \
  do {                                                                         \
    const f16* p_ = &lds[32768 + (2 * (buf) + bh) * 8192 + bq * 4096 +         \
                         (ch) * 2 * 1024];                                     \
    bF[(ch) * 2][0] = *(const f16x8*)(p_ + vR0);                               \
    bF[(ch) * 2][1] = *(const f16x8*)(p_ + vR1);                               \
    bF[(ch) * 2 + 1][0] = *(const f16x8*)(p_ + 1024 + vR0);                    \
    bF[(ch) * 2 + 1][1] = *(const f16x8*)(p_ + 1024 + vR1);                    \
  } while (0)

#define MFMA16(rh, ch)                                                         \
  do {                                                                         \
    __builtin_amdgcn_s_setprio(1);                                             \
    _Pragma("unroll") for (int rt = 0; rt < 4; ++rt)                           \
        _Pragma("unroll") for (int ct = 0; ct < 2; ++ct)                       \
        _Pragma("unroll") for (int ks = 0; ks < 2; ++ks)                       \
            acc[(rh) * 4 + rt][(ch) * 2 + ct] =                                \
        __builtin_amdgcn_mfma_f32_16x16x32_f16(                                \
            aF[rt][ks], bF[(ch) * 2 + ct][ks], acc[(rh) * 4 + rt][(ch) * 2 + ct], \
            0, 0, 0);                                                          \
    __builtin_amdgcn_s_setprio(0);                                             \
    __builtin_amdgcn_sched_barrier(0);                                         \
  } while (0)

template <int MODE>
__global__ __launch_bounds__(512, 2) void gemm256_kernel(
    const f16* __restrict__ A, const f16* __restrict__ B, f16* __restrict__ T,
    float* __restrict__ P, const float* __restrict__ gate,
    const float* __restrict__ sgp) {
  constexpr size_t LD = (MODE == 2) ? 36864 : 1024;
  constexpr int NTILES = (MODE == 2) ? 72 : 16;
  __shared__ __align__(16) f16 lds[65536];  // 128 KiB

  int mt, nt, slot, kpart;
  if (MODE == 2) {
    int wg = (blockIdx.x & 7) * 32 + (blockIdx.x >> 3);
    kpart = wg >> 5; mt = (wg >> 2) & 7; nt = wg & 3; slot = 0;
  } else {
    int wg = ((blockIdx.x & 7) * 144) + (blockIdx.x >> 3);
    mt = wg / 144;
    int r144 = wg % 144;
    slot = r144 >> 4; nt = r144 & 15; kpart = 0;
  }

  int t = threadIdx.x, w = t >> 6, l = t & 63;
  int wr = w >> 2, wc = w & 3;
  int bh = wc >> 1, bq = wc & 1;

  int scol = (((l & 7) ^ ((l >> 3) & 7)) * 8);
  size_t stRow = (size_t)(w * 8 + (l >> 3)) * LD;
  size_t aVoff = stRow + scol;
  const f16* Abase;
  const f16* Bbase;
  if (MODE == 2) {
    Abase = A + (size_t)mt * 256 * LD + (size_t)kpart * 4608;
    Bbase = B + (size_t)nt * 256 * LD + (size_t)kpart * 4608;
  } else {
    Abase = A + (size_t)mt * 256 * LD;
    Bbase = B + (size_t)slot * 4096 * 1024 + (size_t)nt * 256 * LD;
  }

  int vR0 = (l & 15) * 64 + (((l >> 4) * 8) ^ ((l & 7) * 8));
  int vR1 = (l & 15) * 64 + ((32 + (l >> 4) * 8) ^ ((l & 7) * 8));

  f16x8 aF[4][2], bF[4][2];
  f32x4 acc[8][4] = {};

  STAGE_B(0, 0); STAGE_B(0, 1);
  STAGE_A(0, 0); STAGE_A(0, 1);
  STAGE_B(1, 0); STAGE_B(1, 1);
  WAITV4;
  BARX;

#pragma unroll 1
  for (int it = 0; it < NTILES / 2 - 1; ++it) {
    int t1 = 2 * it + 1, t2 = 2 * it + 2, t3 = 2 * it + 3;
    RD_A(0, 0); RD_B(0, 0); STAGE_A(t1, 0);
    BARX; WAITL0; MFMA16(0, 0); BARX;
    RD_B(1, 0); STAGE_A(t1, 1);
    BARX; WAITL0; MFMA16(0, 1); BARX;
    RD_A(1, 0); STAGE_B(t2, 0);
    BARX; WAITL0; MFMA16(1, 0); BARX;
    STAGE_B(t2, 1);
    BARX; MFMA16(1, 1); WAITV4; BARX;
    RD_A(0, 1); RD_B(0, 1); STAGE_A(t2, 0);
    BARX; WAITL0; MFMA16(0, 0); BARX;
    RD_B(1, 1); STAGE_A(t2, 1);
    BARX; WAITL0; MFMA16(0, 1); BARX;
    RD_A(1, 1); STAGE_B(t3, 0);
    BARX; WAITL0; MFMA16(1, 0); BARX;
    STAGE_B(t3, 1);
    BARX; MFMA16(1, 1); WAITV4; BARX;
  }
  // peeled last pair: tiles NTILES-2 (b0), NTILES-1 (b1)
  RD_A(0, 0); RD_B(0, 0); STAGE_A(NTILES - 1, 0);
  BARX; WAITL0; MFMA16(0, 0); BARX;
  RD_B(1, 0); STAGE_A(NTILES - 1, 1);
  BARX; WAITL0; MFMA16(0, 1); BARX;
  RD_A(1, 0);
  BARX; WAITL0; MFMA16(1, 0); BARX;
  BARX; MFMA16(1, 1); WAITV0; BARX;
  RD_A(0, 1); RD_B(0, 1);
  BARX; WAITL0; MFMA16(0, 0); BARX;
  RD_B(1, 1);
  BARX; WAITL0; MFMA16(0, 1); BARX;
  RD_A(1, 1);
  BARX; WAITL0; MFMA16(1, 0); BARX;
  MFMA16(1, 1);

  // ---- epilogue: C/D layout col=lane&15, row=(lane>>4)*4+j
  int r0 = (l >> 4) * 4, c0 = l & 15;
  if (MODE == 2) {
    size_t base = ((size_t)kpart << 21);
    int rowbase = mt * 256 + wr * 128;
    int colbase = nt * 256 + wc * 64;
#pragma unroll
    for (int rt = 0; rt < 8; ++rt)
#pragma unroll
      for (int ct = 0; ct < 4; ++ct)
#pragma unroll
        for (int j = 0; j < 4; ++j)
          P[base + (size_t)(rowbase + rt * 16 + r0 + j) * 1024 + colbase +
            ct * 16 + c0] = acc[rt][ct][j];
  } else {
    int rowbase = mt * 256 + wr * 128;
    size_t colbase = (size_t)slot * 4096 + nt * 256 + wc * 64;
    float coef = 0.f;
    if (MODE == 1) {
      int b = mt >> 2;
      float s = sgp[b];
      coef = (slot < 8) ? (1.f - s) * gate[b * 8 + slot] : s;
    }
#pragma unroll
    for (int rt = 0; rt < 8; ++rt) {
#pragma unroll
      for (int ct = 0; ct < 4; ++ct) {
#pragma unroll
        for (int j = 0; j < 4; ++j) {
          size_t idx = (size_t)(rowbase + rt * 16 + r0 + j) * 36864 + colbase +
                       ct * 16 + c0;
          float v = acc[rt][ct][j];
          if (MODE == 0) {
            T[idx] = (f16)v;
          } else {
            float u = (float)T[idx];
            T[idx] = (f16)(v / (1.f + __expf(-v)) * u * coef);
          }
        }
      }
    }
  }
}

// ---------------- sum 8 split-K partials -> fp32 out ------------------------
__global__ void reduce8_kernel(const float* __restrict__ P,
                               float* __restrict__ out, int n4) {
  int i = blockIdx.x * blockDim.x + threadIdx.x;
  if (i < n4) {
    f32x4 s = {0.f, 0.f, 0.f, 0.f};
#pragma unroll
    for (int e = 0; e < 8; ++e) {
      f32x4 v = reinterpret_cast<const f32x4*>(P + ((size_t)e << 21))[i];
      s += v;
    }
    reinterpret_cast<f32x4*>(out)[i] = s;
  }
}

extern "C" void kernel_launch(void* const* d_in, const int* in_sizes, int n_in,
                              void* d_out, int out_size, void* d_ws,
                              size_t ws_size, hipStream_t stream) {
  const float* h    = (const float*)d_in[0];
  const float* gate = (const float*)d_in[1];
  const float* sgp  = (const float*)d_in[2];
  const float* Wg   = (const float*)d_in[3];
  const float* Wu   = (const float*)d_in[4];
  const float* Wd   = (const float*)d_in[5];
  const float* Sg   = (const float*)d_in[6];
  const float* Su   = (const float*)d_in[7];
  const float* Sd   = (const float*)d_in[8];

  const size_t SZ_HB = 4194304;      // 2048*1024 f16
  const size_t SZ_W  = 75497472;     // 9*4096*1024 f16 (WgT/WuT slabs; WdT mega)
  const size_t SZ_T  = 150994944;    // 2048*36864 f16
  const size_t SZ_P  = 67108864;     // 8*2048*1024 f32
  char* ws = (char*)d_ws;
  f16*   hb  = (f16*)(ws);
  f16*   WgT = (f16*)(ws + SZ_HB);
  f16*   WuT = (f16*)(ws + SZ_HB + SZ_W);
  f16*   WdT = (f16*)(ws + SZ_HB + 2 * SZ_W);  // [1024][36864]: [d][slot*4096+f]
  f16*   T   = (f16*)(ws + SZ_HB + 3 * SZ_W);
  float* P   = (float*)(ws + SZ_HB + 3 * SZ_W + SZ_T);
  size_t need = SZ_HB + 3 * SZ_W + SZ_T + SZ_P;
  if (ws_size < need) {
    fprintf(stderr, "kernel_launch: ws too small (%zu < %zu)\n", ws_size, need);
    return;
  }
  float* out = (float*)d_out;

  cvt_f32_f16_kernel<<<2048, 256, 0, stream>>>(h, hb, 524288);
  // Wg [1024][4096] -> WgT slab [4096][1024]
  tr_cvt2_kernel<<<dim3(64, 16, 9), 256, 0, stream>>>(
      Wg, Sg, WgT, 4096ull * 1024, 4096, 1024, 8);
  tr_cvt2_kernel<<<dim3(64, 16, 9), 256, 0, stream>>>(
      Wu, Su, WuT, 4096ull * 1024, 4096, 1024, 8);
  // Wd [4096][1024] -> WdT mega [1024][36864], col offset slot*4096
  tr_cvt2_kernel<<<dim3(16, 64, 9), 256, 0, stream>>>(
      Wd, Sd, WdT, 4096, 1024, 36864, 8);

  gemm256_kernel<0><<<1152, 512, 0, stream>>>(hb, WuT, T, nullptr, nullptr, nullptr);
  gemm256_kernel<1><<<1152, 512, 0, stream>>>(hb, WgT, T, nullptr, gate, sgp);
  gemm256_kernel<2><<<256, 512, 0, stream>>>(T, WdT, nullptr, P, nullptr, nullptr);
  reduce8_kernel<<<2048, 256, 0, stream>>>(P, out, 524288);
}

// Round 5
// 576.561 us; speedup vs baseline: 1.8429x; 1.1301x over previous
//
#include <hip/hip_runtime.h>
#include <cstdio>
#include <cstdint>

typedef _Float16 f16;
typedef _Float16 f16x4 __attribute__((ext_vector_type(4)));
typedef _Float16 f16x8 __attribute__((ext_vector_type(8)));
typedef float f32x4 __attribute__((ext_vector_type(4)));

#define GLL16(gp, lp)                                                          \
  __builtin_amdgcn_global_load_lds(                                            \
      (const __attribute__((address_space(1))) void*)(gp),                     \
      (__attribute__((address_space(3))) void*)(lp), 16, 0, 0)

#define BARX __builtin_amdgcn_s_barrier()
#define WAITV4 { asm volatile("s_waitcnt vmcnt(4)" ::: "memory"); __builtin_amdgcn_sched_barrier(0); }
#define WAITV0 { asm volatile("s_waitcnt vmcnt(0)" ::: "memory"); __builtin_amdgcn_sched_barrier(0); }
#define WAITL0 { asm volatile("s_waitcnt lgkmcnt(0)" ::: "memory"); __builtin_amdgcn_sched_barrier(0); }

// ---------------- fp32 -> fp16 elementwise (h) ----------------
__global__ void cvt_f32_f16_kernel(const float* __restrict__ in,
                                   f16* __restrict__ out, int n4) {
  int i = blockIdx.x * blockDim.x + threadIdx.x;
  if (i < n4) {
    f32x4 v = reinterpret_cast<const f32x4*>(in)[i];
    f16x4 o;
    o[0] = (f16)v[0]; o[1] = (f16)v[1]; o[2] = (f16)v[2]; o[3] = (f16)v[3];
    reinterpret_cast<f16x4*>(out)[i] = o;
  }
}

// ------- fp32 [R][C] -> fp16 transposed, 64x64 tiles, coalesced stores ------
__global__ void tr_cvt2_kernel(const float* __restrict__ inA,
                               const float* __restrict__ inB,
                               f16* __restrict__ out, size_t slotOff,
                               int C, size_t OS, int nA) {
  int slot = blockIdx.z;
  const float* src = (slot < nA) ? inA + (size_t)slot * 64 * gridDim.y * C : inB;
  f16* dst = out + (size_t)slot * slotOff;
  __shared__ f16 tl[4096];
  int t = threadIdx.x;
  int r0 = blockIdx.y * 64, c0 = blockIdx.x * 64;
  int br = (t >> 4) * 4, bc = (t & 15) * 4;
  f32x4 v[4];
#pragma unroll
  for (int i = 0; i < 4; ++i)
    v[i] = *(const f32x4*)&src[(size_t)(r0 + br + i) * C + c0 + bc];
#pragma unroll
  for (int cc = 0; cc < 4; ++cc) {
    int c = bc + cc;
    f16x4 o;
    o[0] = (f16)v[0][cc]; o[1] = (f16)v[1][cc];
    o[2] = (f16)v[2][cc]; o[3] = (f16)v[3][cc];
    *(f16x4*)&tl[c * 64 + (br ^ ((c & 7) * 8))] = o;
  }
  __syncthreads();
  int rw = (t & 7) * 8, cw = t >> 3;
#pragma unroll
  for (int j = 0; j < 2; ++j) {
    int c = cw + j * 32;
    f16x8 o = *(const f16x8*)&tl[c * 64 + (rw ^ ((c & 7) * 8))];
    *(f16x8*)&dst[(size_t)(c0 + c) * OS + r0 + rw] = o;
  }
}

// ============ fused UG: T = silu(h@Wg)*(h@Wu)*coef, fat 2-phase =============
// BM=256 BN=128 BK=64, 512 thr / 8 waves (4M x 2N), per-wave 64x64 dual-acc.
// LDS 128KB: per buf {A[4][64][64sw] 32KB at buf*16384; Bg 8KB, Bu 8KB at
// 32768+buf*16384}. Swizzle: k-group slot = kq ^ (row&7) (8 groups of 8 f16).
#define STAGE_A3(NB)                                                           \
  do {                                                                         \
    f16* d_ = &lds[(NB) * 16384 + ldsT];                                       \
    GLL16(aS, d_); GLL16(aS + 65536, d_ + 4096);                               \
    GLL16(aS + 131072, d_ + 8192); GLL16(aS + 196608, d_ + 12288);             \
  } while (0)
#define STAGE_G3(NB)                                                           \
  do {                                                                         \
    f16* d_ = &lds[32768 + (NB) * 16384 + ldsT];                               \
    GLL16(gS, d_); GLL16(gS + 65536, d_ + 4096);                               \
  } while (0)
#define STAGE_U3(NB)                                                           \
  do {                                                                         \
    f16* d_ = &lds[32768 + (NB) * 16384 + 8192 + ldsT];                        \
    GLL16(uS, d_); GLL16(uS + 65536, d_ + 4096);                               \
  } while (0)

#define RD3(BUF, VK)                                                           \
  do {                                                                         \
    const f16* pa_ = &lds[(BUF) * 16384 + wr * 4096 + vRow + (VK)];            \
    aF[0] = *(const f16x8*)(pa_);                                              \
    aF[1] = *(const f16x8*)(pa_ + 1024);                                       \
    aF[2] = *(const f16x8*)(pa_ + 2048);                                       \
    aF[3] = *(const f16x8*)(pa_ + 3072);                                       \
    const f16* pg_ = &lds[32768 + (BUF) * 16384 + wc * 4096 + vRow + (VK)];    \
    bG[0] = *(const f16x8*)(pg_);                                              \
    bG[1] = *(const f16x8*)(pg_ + 1024);                                       \
    bG[2] = *(const f16x8*)(pg_ + 2048);                                       \
    bG[3] = *(const f16x8*)(pg_ + 3072);                                       \
    const f16* pu_ = pg_ + 8192;                                               \
    bU[0] = *(const f16x8*)(pu_);                                              \
    bU[1] = *(const f16x8*)(pu_ + 1024);                                       \
    bU[2] = *(const f16x8*)(pu_ + 2048);                                       \
    bU[3] = *(const f16x8*)(pu_ + 3072);                                       \
  } while (0)

#define MFMA32()                                                               \
  do {                                                                         \
    __builtin_amdgcn_s_setprio(1);                                             \
    _Pragma("unroll") for (int mi = 0; mi < 4; ++mi)                           \
        _Pragma("unroll") for (int ni = 0; ni < 4; ++ni) {                     \
      ag[mi][ni] = __builtin_amdgcn_mfma_f32_16x16x32_f16(aF[mi], bG[ni],      \
                                                          ag[mi][ni], 0, 0, 0);\
      au[mi][ni] = __builtin_amdgcn_mfma_f32_16x16x32_f16(aF[mi], bU[ni],      \
                                                          au[mi][ni], 0, 0, 0);\
    }                                                                          \
    __builtin_amdgcn_s_setprio(0);                                             \
    __builtin_amdgcn_sched_barrier(0);                                         \
  } while (0)

#define BODY3(BUF, DOSTA, DOSTB)                                               \
  do {                                                                         \
    RD3(BUF, vK0);                                                             \
    if (DOSTA) { STAGE_A3((BUF) ^ 1); }                                        \
    BARX; WAITL0;                                                              \
    MFMA32();                                                                  \
    BARX;                                                                      \
    RD3(BUF, vK1);                                                             \
    if (DOSTB) {                                                               \
      STAGE_G3((BUF) ^ 1); STAGE_U3((BUF) ^ 1);                                \
      aS += 64; gS += 64; uS += 64;                                            \
    }                                                                          \
    BARX; WAITL0;                                                              \
    MFMA32();                                                                  \
    if (DOSTB) { WAITV0; }                                                     \
    BARX;                                                                      \
  } while (0)

__global__ __launch_bounds__(512, 2) void gemmUG3_kernel(
    const f16* __restrict__ A, const f16* __restrict__ Bg,
    const f16* __restrict__ Bu, f16* __restrict__ T,
    const float* __restrict__ gate, const float* __restrict__ sgp) {
  __shared__ __align__(16) f16 lds[65536];  // 128 KiB

  // XCD-chunked: logical = xcd*288 + i; mt fastest within chunk.
  int lgl = (blockIdx.x & 7) * 288 + (blockIdx.x >> 3);
  int mt = lgl & 7;            // 0..7   (256 rows each)
  int ntg = lgl >> 3;          // 0..287 (128 cols each)
  int slot = ntg >> 5;         // 0..8

  int t = threadIdx.x, w = t >> 6, l = t & 63;
  int wr = w >> 1, wc = w & 1;  // wave grid 4M x 2N

  // staging: thread t covers row (t>>3)+i*64, k-group slot t&7 (src XOR'd)
  int kqs = (((t & 7) ^ ((t >> 3) & 7)) * 8);
  const f16* aS = A + (size_t)(mt * 256 + (t >> 3)) * 1024 + kqs;
  const f16* gS = Bg + (size_t)slot * 4194304 +
                  (size_t)((ntg & 31) * 128 + (t >> 3)) * 1024 + kqs;
  const f16* uS = Bu + (size_t)slot * 4194304 +
                  (size_t)((ntg & 31) * 128 + (t >> 3)) * 1024 + kqs;
  int ldsT = t * 8;

  // frag read offsets: row=(l&15), k-slot = (ks*4 + (l>>4)) ^ (l&7)
  int vRow = (l & 15) * 64;
  int vK0 = (((l >> 4) ^ (l & 7))) * 8;
  int vK1 = (((4 + (l >> 4)) ^ (l & 7))) * 8;

  f16x8 aF[4], bG[4], bU[4];
  f32x4 ag[4][4] = {}, au[4][4] = {};

  // prologue: stage tile 0 -> buf0
  STAGE_A3(0); STAGE_G3(0); STAGE_U3(0);
  aS += 64; gS += 64; uS += 64;
  WAITV0; BARX;

#pragma unroll 1
  for (int it = 0; it < 7; ++it) {
    BODY3(0, 1, 1);
    BODY3(1, 1, 1);
  }
  BODY3(0, 1, 1);   // tile 14, stages tile 15
  BODY3(1, 0, 0);   // tile 15

  // epilogue: C/D col=lane&15, row=(lane>>4)*4+j
  int r0 = (l >> 4) * 4, c0 = l & 15;
  int rowb = mt * 256 + wr * 64;
  size_t colb = (size_t)ntg * 128 + wc * 64;
  int b = mt >> 2;
  float s = sgp[b];
  float coef = (slot < 8) ? (1.f - s) * gate[b * 8 + slot] : s;
#pragma unroll
  for (int mi = 0; mi < 4; ++mi) {
#pragma unroll
    for (int ni = 0; ni < 4; ++ni) {
#pragma unroll
      for (int j = 0; j < 4; ++j) {
        float g = ag[mi][ni][j];
        float u = au[mi][ni][j];
        T[(size_t)(rowb + mi * 16 + r0 + j) * 36864 + colb + ni * 16 + c0] =
            (f16)(g / (1.f + __expf(-g)) * u * coef);
      }
    }
  }
}

// =================== 256x256 8-phase GEMM (mega down-proj) ==================
#define STAGE_A(tile, hf)                                                      \
  do {                                                                         \
    const f16* g_ = Abase + (size_t)((hf) * 128) * LD + (tile) * 64 + aVoff;   \
    f16* d_ = &lds[(2 * ((tile) & 1) + (hf)) * 8192 + w * 512];                \
    GLL16(g_, d_);                                                             \
    GLL16(g_ + (size_t)64 * LD, d_ + 4096);                                    \
  } while (0)
#define STAGE_B(tile, hf)                                                      \
  do {                                                                         \
    const f16* g_ = Bbase + (size_t)((hf) * 128) * LD + (tile) * 64 + aVoff;   \
    f16* d_ = &lds[32768 + (2 * ((tile) & 1) + (hf)) * 8192 + w * 512];        \
    GLL16(g_, d_);                                                             \
    GLL16(g_ + (size_t)64 * LD, d_ + 4096);                                    \
  } while (0)

#define RD_A(rh, buf)                                                          \
  do {                                                                         \
    const f16* p_ = &lds[(2 * (buf) + wr) * 8192 + (rh) * 4096];               \
    aFd[0][0] = *(const f16x8*)(p_ + 0 * 1024 + vR0);                          \
    aFd[0][1] = *(const f16x8*)(p_ + 0 * 1024 + vR1);                          \
    aFd[1][0] = *(const f16x8*)(p_ + 1 * 1024 + vR0);                          \
    aFd[1][1] = *(const f16x8*)(p_ + 1 * 1024 + vR1);                          \
    aFd[2][0] = *(const f16x8*)(p_ + 2 * 1024 + vR0);                          \
    aFd[2][1] = *(const f16x8*)(p_ + 2 * 1024 + vR1);                          \
    aFd[3][0] = *(const f16x8*)(p_ + 3 * 1024 + vR0);                          \
    aFd[3][1] = *(const f16x8*)(p_ + 3 * 1024 + vR1);                          \
  } while (0)
#define RD_B(ch, buf)                                                          \
  do {                                                                         \
    const f16* p_ = &lds[32768 + (2 * (buf) + bh) * 8192 + bq * 4096 +         \
                         (ch) * 2 * 1024];                                     \
    bFd[(ch) * 2][0] = *(const f16x8*)(p_ + vR0);                              \
    bFd[(ch) * 2][1] = *(const f16x8*)(p_ + vR1);                              \
    bFd[(ch) * 2 + 1][0] = *(const f16x8*)(p_ + 1024 + vR0);                   \
    bFd[(ch) * 2 + 1][1] = *(const f16x8*)(p_ + 1024 + vR1);                   \
  } while (0)

#define MFMA16(rh, ch)                                                         \
  do {                                                                         \
    __builtin_amdgcn_s_setprio(1);                                             \
    _Pragma("unroll") for (int rt = 0; rt < 4; ++rt)                           \
        _Pragma("unroll") for (int ct = 0; ct < 2; ++ct)                       \
        _Pragma("unroll") for (int ks = 0; ks < 2; ++ks)                       \
            acc[(rh) * 4 + rt][(ch) * 2 + ct] =                                \
        __builtin_amdgcn_mfma_f32_16x16x32_f16(                                \
            aFd[rt][ks], bFd[(ch) * 2 + ct][ks],                               \
            acc[(rh) * 4 + rt][(ch) * 2 + ct], 0, 0, 0);                       \
    __builtin_amdgcn_s_setprio(0);                                             \
    __builtin_amdgcn_sched_barrier(0);                                         \
  } while (0)

__global__ __launch_bounds__(512, 2) void gemmD_kernel(
    const f16* __restrict__ A, const f16* __restrict__ B,
    float* __restrict__ P) {
  constexpr size_t LD = 36864;
  constexpr int NTILES = 72;
  __shared__ __align__(16) f16 lds[65536];

  int wg = (blockIdx.x & 7) * 32 + (blockIdx.x >> 3);
  int kpart = wg >> 5, mt = (wg >> 2) & 7, nt = wg & 3;

  int t = threadIdx.x, w = t >> 6, l = t & 63;
  int wr = w >> 2, wc = w & 3;
  int bh = wc >> 1, bq = wc & 1;

  int scol = (((l & 7) ^ ((l >> 3) & 7)) * 8);
  size_t stRow = (size_t)(w * 8 + (l >> 3)) * LD;
  size_t aVoff = stRow + scol;
  const f16* Abase = A + (size_t)mt * 256 * LD + (size_t)kpart * 4608;
  const f16* Bbase = B + (size_t)nt * 256 * LD + (size_t)kpart * 4608;

  int vR0 = (l & 15) * 64 + (((l >> 4) * 8) ^ ((l & 7) * 8));
  int vR1 = (l & 15) * 64 + ((32 + (l >> 4) * 8) ^ ((l & 7) * 8));

  f16x8 aFd[4][2], bFd[4][2];
  f32x4 acc[8][4] = {};

  STAGE_B(0, 0); STAGE_B(0, 1);
  STAGE_A(0, 0); STAGE_A(0, 1);
  STAGE_B(1, 0); STAGE_B(1, 1);
  WAITV4;
  BARX;

#pragma unroll 1
  for (int it = 0; it < NTILES / 2 - 1; ++it) {
    int t1 = 2 * it + 1, t2 = 2 * it + 2, t3 = 2 * it + 3;
    RD_A(0, 0); RD_B(0, 0); STAGE_A(t1, 0);
    BARX; WAITL0; MFMA16(0, 0); BARX;
    RD_B(1, 0); STAGE_A(t1, 1);
    BARX; WAITL0; MFMA16(0, 1); BARX;
    RD_A(1, 0); STAGE_B(t2, 0);
    BARX; WAITL0; MFMA16(1, 0); BARX;
    STAGE_B(t2, 1);
    BARX; MFMA16(1, 1); WAITV4; BARX;
    RD_A(0, 1); RD_B(0, 1); STAGE_A(t2, 0);
    BARX; WAITL0; MFMA16(0, 0); BARX;
    RD_B(1, 1); STAGE_A(t2, 1);
    BARX; WAITL0; MFMA16(0, 1); BARX;
    RD_A(1, 1); STAGE_B(t3, 0);
    BARX; WAITL0; MFMA16(1, 0); BARX;
    STAGE_B(t3, 1);
    BARX; MFMA16(1, 1); WAITV4; BARX;
  }
  RD_A(0, 0); RD_B(0, 0); STAGE_A(NTILES - 1, 0);
  BARX; WAITL0; MFMA16(0, 0); BARX;
  RD_B(1, 0); STAGE_A(NTILES - 1, 1);
  BARX; WAITL0; MFMA16(0, 1); BARX;
  RD_A(1, 0);
  BARX; WAITL0; MFMA16(1, 0); BARX;
  BARX; MFMA16(1, 1); WAITV0; BARX;
  RD_A(0, 1); RD_B(0, 1);
  BARX; WAITL0; MFMA16(0, 0); BARX;
  RD_B(1, 1);
  BARX; WAITL0; MFMA16(0, 1); BARX;
  RD_A(1, 1);
  BARX; WAITL0; MFMA16(1, 0); BARX;
  MFMA16(1, 1);

  int r0 = (l >> 4) * 4, c0 = l & 15;
  size_t base = ((size_t)kpart << 21);
  int rowbase = mt * 256 + wr * 128;
  int colbase = nt * 256 + wc * 64;
#pragma unroll
  for (int rt = 0; rt < 8; ++rt)
#pragma unroll
    for (int ct = 0; ct < 4; ++ct)
#pragma unroll
      for (int j = 0; j < 4; ++j)
        P[base + (size_t)(rowbase + rt * 16 + r0 + j) * 1024 + colbase +
          ct * 16 + c0] = acc[rt][ct][j];
}

// ---------------- sum 8 split-K partials -> fp32 out ------------------------
__global__ void reduce8_kernel(const float* __restrict__ P,
                               float* __restrict__ out, int n4) {
  int i = blockIdx.x * blockDim.x + threadIdx.x;
  if (i < n4) {
    f32x4 s = {0.f, 0.f, 0.f, 0.f};
#pragma unroll
    for (int e = 0; e < 8; ++e) {
      f32x4 v = reinterpret_cast<const f32x4*>(P + ((size_t)e << 21))[i];
      s += v;
    }
    reinterpret_cast<f32x4*>(out)[i] = s;
  }
}

extern "C" void kernel_launch(void* const* d_in, const int* in_sizes, int n_in,
                              void* d_out, int out_size, void* d_ws,
                              size_t ws_size, hipStream_t stream) {
  const float* h    = (const float*)d_in[0];
  const float* gate = (const float*)d_in[1];
  const float* sgp  = (const float*)d_in[2];
  const float* Wg   = (const float*)d_in[3];
  const float* Wu   = (const float*)d_in[4];
  const float* Wd   = (const float*)d_in[5];
  const float* Sg   = (const float*)d_in[6];
  const float* Su   = (const float*)d_in[7];
  const float* Sd   = (const float*)d_in[8];

  const size_t SZ_HB = 4194304;      // 2048*1024 f16
  const size_t SZ_W  = 75497472;     // 9*4096*1024 f16
  const size_t SZ_T  = 150994944;    // 2048*36864 f16
  const size_t SZ_P  = 67108864;     // 8*2048*1024 f32
  char* ws = (char*)d_ws;
  f16*   hb  = (f16*)(ws);
  f16*   WgT = (f16*)(ws + SZ_HB);
  f16*   WuT = (f16*)(ws + SZ_HB + SZ_W);
  f16*   WdT = (f16*)(ws + SZ_HB + 2 * SZ_W);  // [1024][36864] mega
  f16*   T   = (f16*)(ws + SZ_HB + 3 * SZ_W);
  float* P   = (float*)(ws + SZ_HB + 3 * SZ_W + SZ_T);
  size_t need = SZ_HB + 3 * SZ_W + SZ_T + SZ_P;
  if (ws_size < need) {
    fprintf(stderr, "kernel_launch: ws too small (%zu < %zu)\n", ws_size, need);
    return;
  }
  float* out = (float*)d_out;

  cvt_f32_f16_kernel<<<2048, 256, 0, stream>>>(h, hb, 524288);
  tr_cvt2_kernel<<<dim3(64, 16, 9), 256, 0, stream>>>(
      Wg, Sg, WgT, 4096ull * 1024, 4096, 1024, 8);
  tr_cvt2_kernel<<<dim3(64, 16, 9), 256, 0, stream>>>(
      Wu, Su, WuT, 4096ull * 1024, 4096, 1024, 8);
  tr_cvt2_kernel<<<dim3(16, 64, 9), 256, 0, stream>>>(
      Wd, Sd, WdT, 4096, 1024, 36864, 8);

  gemmUG3_kernel<<<2304, 512, 0, stream>>>(hb, WgT, WuT, T, gate, sgp);
  gemmD_kernel<<<256, 512, 0, stream>>>(T, WdT, P);
  reduce8_kernel<<<2048, 256, 0, stream>>>(P, out, 524288);
}

// Round 6
// 564.750 us; speedup vs baseline: 1.8814x; 1.0209x over previous
//
#include <hip/hip_runtime.h>
#include <cstdio>
#include <cstdint>

typedef _Float16 f16;
typedef _Float16 f16x4 __attribute__((ext_vector_type(4)));
typedef _Float16 f16x8 __attribute__((ext_vector_type(8)));
typedef float f32x4 __attribute__((ext_vector_type(4)));

#define GLL16(gp, lp)                                                          \
  __builtin_amdgcn_global_load_lds(                                            \
      (const __attribute__((address_space(1))) void*)(gp),                     \
      (__attribute__((address_space(3))) void*)(lp), 16, 0, 0)

#define BARX __builtin_amdgcn_s_barrier()
#define WAITV8 { asm volatile("s_waitcnt vmcnt(8)" ::: "memory"); __builtin_amdgcn_sched_barrier(0); }
#define WAITV4 { asm volatile("s_waitcnt vmcnt(4)" ::: "memory"); __builtin_amdgcn_sched_barrier(0); }
#define WAITV0 { asm volatile("s_waitcnt vmcnt(0)" ::: "memory"); __builtin_amdgcn_sched_barrier(0); }
#define WAITL0 { asm volatile("s_waitcnt lgkmcnt(0)" ::: "memory"); __builtin_amdgcn_sched_barrier(0); }

// ---------------- fp32 -> fp16 elementwise (h) ----------------
__global__ void cvt_f32_f16_kernel(const float* __restrict__ in,
                                   f16* __restrict__ out, int n4) {
  int i = blockIdx.x * blockDim.x + threadIdx.x;
  if (i < n4) {
    f32x4 v = reinterpret_cast<const f32x4*>(in)[i];
    f16x4 o;
    o[0] = (f16)v[0]; o[1] = (f16)v[1]; o[2] = (f16)v[2]; o[3] = (f16)v[3];
    reinterpret_cast<f16x4*>(out)[i] = o;
  }
}

// ------- fp32 [R][C] -> fp16 transposed, 64x64 tiles, coalesced stores ------
__global__ void tr_cvt2_kernel(const float* __restrict__ inA,
                               const float* __restrict__ inB,
                               f16* __restrict__ out, size_t slotOff,
                               int C, size_t OS, int nA) {
  int slot = blockIdx.z;
  const float* src = (slot < nA) ? inA + (size_t)slot * 64 * gridDim.y * C : inB;
  f16* dst = out + (size_t)slot * slotOff;
  __shared__ f16 tl[4096];
  int t = threadIdx.x;
  int r0 = blockIdx.y * 64, c0 = blockIdx.x * 64;
  int br = (t >> 4) * 4, bc = (t & 15) * 4;
  f32x4 v[4];
#pragma unroll
  for (int i = 0; i < 4; ++i)
    v[i] = *(const f32x4*)&src[(size_t)(r0 + br + i) * C + c0 + bc];
#pragma unroll
  for (int cc = 0; cc < 4; ++cc) {
    int c = bc + cc;
    f16x4 o;
    o[0] = (f16)v[0][cc]; o[1] = (f16)v[1][cc];
    o[2] = (f16)v[2][cc]; o[3] = (f16)v[3][cc];
    *(f16x4*)&tl[c * 64 + (br ^ ((c & 7) * 8))] = o;
  }
  __syncthreads();
  int rw = (t & 7) * 8, cw = t >> 3;
#pragma unroll
  for (int j = 0; j < 2; ++j) {
    int c = cw + j * 32;
    f16x8 o = *(const f16x8*)&tl[c * 64 + (rw ^ ((c & 7) * 8))];
    *(f16x8*)&dst[(size_t)(c0 + c) * OS + r0 + rw] = o;
  }
}

// ============ fused UG: T = silu(h@Wg)*(h@Wu)*coef ==========================
// BM=256 BN=128 BK=64, 512 thr / 8 waves (4M x 2N), per-wave 64x64 dual-acc.
// 2 barriers/K-tile, counted vmcnt(8), 2-tile prefetch depth.
// LDS 128KB: per buf {A 32KB at buf*16384(f16); Bg 8KB + Bu 8KB at
// 32768+buf*16384}. Swizzle: k-group slot = kq ^ (row&7) (8 groups of 8 f16).
#define STAGE_T(NB, TILE)                                                      \
  do {                                                                         \
    const f16* a_ = aS + (size_t)(TILE) * 64;                                  \
    f16* da_ = &lds[(NB) * 16384 + ldsT];                                      \
    GLL16(a_, da_); GLL16(a_ + 65536, da_ + 4096);                             \
    GLL16(a_ + 131072, da_ + 8192); GLL16(a_ + 196608, da_ + 12288);           \
    const f16* g_ = gS + (size_t)(TILE) * 64;                                  \
    f16* dg_ = &lds[32768 + (NB) * 16384 + ldsT];                              \
    GLL16(g_, dg_); GLL16(g_ + 65536, dg_ + 4096);                             \
    const f16* u_ = uS + (size_t)(TILE) * 64;                                  \
    GLL16(u_, dg_ + 8192); GLL16(u_ + 65536, dg_ + 12288);                     \
  } while (0)

#define RD3(BUF, VK)                                                           \
  do {                                                                         \
    const f16* pa_ = &lds[(BUF) * 16384 + wr * 4096 + vRow + (VK)];            \
    aF[0] = *(const f16x8*)(pa_);                                              \
    aF[1] = *(const f16x8*)(pa_ + 1024);                                       \
    aF[2] = *(const f16x8*)(pa_ + 2048);                                       \
    aF[3] = *(const f16x8*)(pa_ + 3072);                                       \
    const f16* pg_ = &lds[32768 + (BUF) * 16384 + wc * 4096 + vRow + (VK)];    \
    bG[0] = *(const f16x8*)(pg_);                                              \
    bG[1] = *(const f16x8*)(pg_ + 1024);                                       \
    bG[2] = *(const f16x8*)(pg_ + 2048);                                       \
    bG[3] = *(const f16x8*)(pg_ + 3072);                                       \
    const f16* pu_ = pg_ + 8192;                                               \
    bU[0] = *(const f16x8*)(pu_);                                              \
    bU[1] = *(const f16x8*)(pu_ + 1024);                                       \
    bU[2] = *(const f16x8*)(pu_ + 2048);                                       \
    bU[3] = *(const f16x8*)(pu_ + 3072);                                       \
  } while (0)

#define MFMA32()                                                               \
  do {                                                                         \
    __builtin_amdgcn_s_setprio(1);                                             \
    _Pragma("unroll") for (int mi = 0; mi < 4; ++mi)                           \
        _Pragma("unroll") for (int ni = 0; ni < 4; ++ni) {                     \
      ag[mi][ni] = __builtin_amdgcn_mfma_f32_16x16x32_f16(aF[mi], bG[ni],      \
                                                          ag[mi][ni], 0, 0, 0);\
      au[mi][ni] = __builtin_amdgcn_mfma_f32_16x16x32_f16(aF[mi], bU[ni],      \
                                                          au[mi][ni], 0, 0, 0);\
    }                                                                          \
    __builtin_amdgcn_s_setprio(0);                                             \
    __builtin_amdgcn_sched_barrier(0);                                         \
  } while (0)

// Per K-tile: ph1 {RD k0; lgkm0; MFMA} (no barrier); ph2 {RD k1; lgkm0; BARX;
// stage tile+2 into cur (safe: all waves' reads in regs); MFMA; WV; BARX}.
#define BODY4(BUF, TILE, DOST, WV)                                             \
  do {                                                                         \
    RD3(BUF, vK0);                                                             \
    WAITL0;                                                                    \
    MFMA32();                                                                  \
    RD3(BUF, vK1);                                                             \
    WAITL0;                                                                    \
    BARX;                                                                      \
    if (DOST) { STAGE_T(BUF, TILE); }                                          \
    MFMA32();                                                                  \
    WV;                                                                        \
    BARX;                                                                      \
  } while (0)

__global__ __launch_bounds__(512, 2) void gemmUG3_kernel(
    const f16* __restrict__ A, const f16* __restrict__ Bg,
    const f16* __restrict__ Bu, f16* __restrict__ T,
    const float* __restrict__ gate, const float* __restrict__ sgp) {
  __shared__ __align__(16) f16 lds[65536];  // 128 KiB

  // XCD-chunked: logical = xcd*288 + i; mt fastest within chunk.
  int lgl = (blockIdx.x & 7) * 288 + (blockIdx.x >> 3);
  int mt = lgl & 7;            // 0..7   (256 rows each)
  int ntg = lgl >> 3;          // 0..287 (128 cols each)
  int slot = ntg >> 5;         // 0..8

  int t = threadIdx.x, w = t >> 6, l = t & 63;
  int wr = w >> 1, wc = w & 1;  // wave grid 4M x 2N

  // staging: thread t covers row (t>>3)+i*64, k-group slot t&7 (src XOR'd)
  int kqs = (((t & 7) ^ ((t >> 3) & 7)) * 8);
  const f16* aS = A + (size_t)(mt * 256 + (t >> 3)) * 1024 + kqs;
  const f16* gS = Bg + (size_t)slot * 4194304 +
                  (size_t)((ntg & 31) * 128 + (t >> 3)) * 1024 + kqs;
  const f16* uS = Bu + (size_t)slot * 4194304 +
                  (size_t)((ntg & 31) * 128 + (t >> 3)) * 1024 + kqs;
  int ldsT = t * 8;

  // frag read offsets: row=(l&15), k-slot = (ks*4 + (l>>4)) ^ (l&7)
  int vRow = (l & 15) * 64;
  int vK0 = (((l >> 4) ^ (l & 7))) * 8;
  int vK1 = (((4 + (l >> 4)) ^ (l & 7))) * 8;

  f16x8 aF[4], bG[4], bU[4];
  f32x4 ag[4][4] = {}, au[4][4] = {};

  // prologue: stage tiles 0,1 -> bufs 0,1; wait tile0 only (8 still out)
  STAGE_T(0, 0);
  STAGE_T(1, 1);
  WAITV8; BARX;

#pragma unroll 1
  for (int it = 0; it < 7; ++it) {
    BODY4(0, 2 * it + 2, 1, WAITV8);
    BODY4(1, 2 * it + 3, 1, WAITV8);
  }
  BODY4(0, 0, 0, WAITV0);   // tile 14; drain tile-15 loads (1.5 tiles slack)
  BODY4(1, 0, 0, {});       // tile 15

  // epilogue: C/D col=lane&15, row=(lane>>4)*4+j
  int r0 = (l >> 4) * 4, c0 = l & 15;
  int rowb = mt * 256 + wr * 64;
  size_t colb = (size_t)ntg * 128 + wc * 64;
  int b = mt >> 2;
  float s = sgp[b];
  float coef = (slot < 8) ? (1.f - s) * gate[b * 8 + slot] : s;
#pragma unroll
  for (int mi = 0; mi < 4; ++mi) {
#pragma unroll
    for (int ni = 0; ni < 4; ++ni) {
#pragma unroll
      for (int j = 0; j < 4; ++j) {
        float g = ag[mi][ni][j];
        float u = au[mi][ni][j];
        T[(size_t)(rowb + mi * 16 + r0 + j) * 36864 + colb + ni * 16 + c0] =
            (f16)(g / (1.f + __expf(-g)) * u * coef);
      }
    }
  }
}

// =================== 256x256 8-phase GEMM (mega down-proj) ==================
#define STAGE_A(tile, hf)                                                      \
  do {                                                                         \
    const f16* g_ = Abase + (size_t)((hf) * 128) * LD + (tile) * 64 + aVoff;   \
    f16* d_ = &lds[(2 * ((tile) & 1) + (hf)) * 8192 + w * 512];                \
    GLL16(g_, d_);                                                             \
    GLL16(g_ + (size_t)64 * LD, d_ + 4096);                                    \
  } while (0)
#define STAGE_B(tile, hf)                                                      \
  do {                                                                         \
    const f16* g_ = Bbase + (size_t)((hf) * 128) * LD + (tile) * 64 + aVoff;   \
    f16* d_ = &lds[32768 + (2 * ((tile) & 1) + (hf)) * 8192 + w * 512];        \
    GLL16(g_, d_);                                                             \
    GLL16(g_ + (size_t)64 * LD, d_ + 4096);                                    \
  } while (0)

#define RD_A(rh, buf)                                                          \
  do {                                                                         \
    const f16* p_ = &lds[(2 * (buf) + wr) * 8192 + (rh) * 4096];               \
    aFd[0][0] = *(const f16x8*)(p_ + 0 * 1024 + vR0);                          \
    aFd[0][1] = *(const f16x8*)(p_ + 0 * 1024 + vR1);                          \
    aFd[1][0] = *(const f16x8*)(p_ + 1 * 1024 + vR0);                          \
    aFd[1][1] = *(const f16x8*)(p_ + 1 * 1024 + vR1);                          \
    aFd[2][0] = *(const f16x8*)(p_ + 2 * 1024 + vR0);                          \
    aFd[2][1] = *(const f16x8*)(p_ + 2 * 1024 + vR1);                          \
    aFd[3][0] = *(const f16x8*)(p_ + 3 * 1024 + vR0);                          \
    aFd[3][1] = *(const f16x8*)(p_ + 3 * 1024 + vR1);                          \
  } while (0)
#define RD_B(ch, buf)                                                          \
  do {                                                                         \
    const f16* p_ = &lds[32768 + (2 * (buf) + bh) * 8192 + bq * 4096 +         \
                         (ch) * 2 * 1024];                                     \
    bFd[(ch) * 2][0] = *(const f16x8*)(p_ + vR0);                              \
    bFd[(ch) * 2][1] = *(const f16x8*)(p_ + vR1);                              \
    bFd[(ch) * 2 + 1][0] = *(const f16x8*)(p_ + 1024 + vR0);                   \
    bFd[(ch) * 2 + 1][1] = *(const f16x8*)(p_ + 1024 + vR1);                   \
  } while (0)

#define MFMA16(rh, ch)                                                         \
  do {                                                                         \
    __builtin_amdgcn_s_setprio(1);                                             \
    _Pragma("unroll") for (int rt = 0; rt < 4; ++rt)                           \
        _Pragma("unroll") for (int ct = 0; ct < 2; ++ct)                       \
        _Pragma("unroll") for (int ks = 0; ks < 2; ++ks)                       \
            acc[(rh) * 4 + rt][(ch) * 2 + ct] =                                \
        __builtin_amdgcn_mfma_f32_16x16x32_f16(                                \
            aFd[rt][ks], bFd[(ch) * 2 + ct][ks],                               \
            acc[(rh) * 4 + rt][(ch) * 2 + ct], 0, 0, 0);                       \
    __builtin_amdgcn_s_setprio(0);                                             \
    __builtin_amdgcn_sched_barrier(0);                                         \
  } while (0)

__global__ __launch_bounds__(512, 2) void gemmD_kernel(
    const f16* __restrict__ A, const f16* __restrict__ B,
    float* __restrict__ P) {
  constexpr size_t LD = 36864;
  constexpr int NTILES = 72;
  __shared__ __align__(16) f16 lds[65536];

  int wg = (blockIdx.x & 7) * 32 + (blockIdx.x >> 3);
  int kpart = wg >> 5, mt = (wg >> 2) & 7, nt = wg & 3;

  int t = threadIdx.x, w = t >> 6, l = t & 63;
  int wr = w >> 2, wc = w & 3;
  int bh = wc >> 1, bq = wc & 1;

  int scol = (((l & 7) ^ ((l >> 3) & 7)) * 8);
  size_t stRow = (size_t)(w * 8 + (l >> 3)) * LD;
  size_t aVoff = stRow + scol;
  const f16* Abase = A + (size_t)mt * 256 * LD + (size_t)kpart * 4608;
  const f16* Bbase = B + (size_t)nt * 256 * LD + (size_t)kpart * 4608;

  int vR0 = (l & 15) * 64 + (((l >> 4) * 8) ^ ((l & 7) * 8));
  int vR1 = (l & 15) * 64 + ((32 + (l >> 4) * 8) ^ ((l & 7) * 8));

  f16x8 aFd[4][2], bFd[4][2];
  f32x4 acc[8][4] = {};

  STAGE_B(0, 0); STAGE_B(0, 1);
  STAGE_A(0, 0); STAGE_A(0, 1);
  STAGE_B(1, 0); STAGE_B(1, 1);
  WAITV4;
  BARX;

#pragma unroll 1
  for (int it = 0; it < NTILES / 2 - 1; ++it) {
    int t1 = 2 * it + 1, t2 = 2 * it + 2, t3 = 2 * it + 3;
    RD_A(0, 0); RD_B(0, 0); STAGE_A(t1, 0);
    BARX; WAITL0; MFMA16(0, 0); BARX;
    RD_B(1, 0); STAGE_A(t1, 1);
    BARX; WAITL0; MFMA16(0, 1); BARX;
    RD_A(1, 0); STAGE_B(t2, 0);
    BARX; WAITL0; MFMA16(1, 0); BARX;
    STAGE_B(t2, 1);
    BARX; MFMA16(1, 1); WAITV4; BARX;
    RD_A(0, 1); RD_B(0, 1); STAGE_A(t2, 0);
    BARX; WAITL0; MFMA16(0, 0); BARX;
    RD_B(1, 1); STAGE_A(t2, 1);
    BARX; WAITL0; MFMA16(0, 1); BARX;
    RD_A(1, 1); STAGE_B(t3, 0);
    BARX; WAITL0; MFMA16(1, 0); BARX;
    STAGE_B(t3, 1);
    BARX; MFMA16(1, 1); WAITV4; BARX;
  }
  RD_A(0, 0); RD_B(0, 0); STAGE_A(NTILES - 1, 0);
  BARX; WAITL0; MFMA16(0, 0); BARX;
  RD_B(1, 0); STAGE_A(NTILES - 1, 1);
  BARX; WAITL0; MFMA16(0, 1); BARX;
  RD_A(1, 0);
  BARX; WAITL0; MFMA16(1, 0); BARX;
  BARX; MFMA16(1, 1); WAITV0; BARX;
  RD_A(0, 1); RD_B(0, 1);
  BARX; WAITL0; MFMA16(0, 0); BARX;
  RD_B(1, 1);
  BARX; WAITL0; MFMA16(0, 1); BARX;
  RD_A(1, 1);
  BARX; WAITL0; MFMA16(1, 0); BARX;
  MFMA16(1, 1);

  int r0 = (l >> 4) * 4, c0 = l & 15;
  size_t base = ((size_t)kpart << 21);
  int rowbase = mt * 256 + wr * 128;
  int colbase = nt * 256 + wc * 64;
#pragma unroll
  for (int rt = 0; rt < 8; ++rt)
#pragma unroll
    for (int ct = 0; ct < 4; ++ct)
#pragma unroll
      for (int j = 0; j < 4; ++j)
        P[base + (size_t)(rowbase + rt * 16 + r0 + j) * 1024 + colbase +
          ct * 16 + c0] = acc[rt][ct][j];
}

// ---------------- sum 8 split-K partials -> fp32 out ------------------------
__global__ void reduce8_kernel(const float* __restrict__ P,
                               float* __restrict__ out, int n4) {
  int i = blockIdx.x * blockDim.x + threadIdx.x;
  if (i < n4) {
    f32x4 s = {0.f, 0.f, 0.f, 0.f};
#pragma unroll
    for (int e = 0; e < 8; ++e) {
      f32x4 v = reinterpret_cast<const f32x4*>(P + ((size_t)e << 21))[i];
      s += v;
    }
    reinterpret_cast<f32x4*>(out)[i] = s;
  }
}

extern "C" void kernel_launch(void* const* d_in, const int* in_sizes, int n_in,
                              void* d_out, int out_size, void* d_ws,
                              size_t ws_size, hipStream_t stream) {
  const float* h    = (const float*)d_in[0];
  const float* gate = (const float*)d_in[1];
  const float* sgp  = (const float*)d_in[2];
  const float* Wg   = (const float*)d_in[3];
  const float* Wu   = (const float*)d_in[4];
  const float* Wd   = (const float*)d_in[5];
  const float* Sg   = (const float*)d_in[6];
  const float* Su   = (const float*)d_in[7];
  const float* Sd   = (const float*)d_in[8];

  const size_t SZ_HB = 4194304;      // 2048*1024 f16
  const size_t SZ_W  = 75497472;     // 9*4096*1024 f16
  const size_t SZ_T  = 150994944;    // 2048*36864 f16
  const size_t SZ_P  = 67108864;     // 8*2048*1024 f32
  char* ws = (char*)d_ws;
  f16*   hb  = (f16*)(ws);
  f16*   WgT = (f16*)(ws + SZ_HB);
  f16*   WuT = (f16*)(ws + SZ_HB + SZ_W);
  f16*   WdT = (f16*)(ws + SZ_HB + 2 * SZ_W);  // [1024][36864] mega
  f16*   T   = (f16*)(ws + SZ_HB + 3 * SZ_W);
  float* P   = (float*)(ws + SZ_HB + 3 * SZ_W + SZ_T);
  size_t need = SZ_HB + 3 * SZ_W + SZ_T + SZ_P;
  if (ws_size < need) {
    fprintf(stderr, "kernel_launch: ws too small (%zu < %zu)\n", ws_size, need);
    return;
  }
  float* out = (float*)d_out;

  cvt_f32_f16_kernel<<<2048, 256, 0, stream>>>(h, hb, 524288);
  tr_cvt2_kernel<<<dim3(64, 16, 9), 256, 0, stream>>>(
      Wg, Sg, WgT, 4096ull * 1024, 4096, 1024, 8);
  tr_cvt2_kernel<<<dim3(64, 16, 9), 256, 0, stream>>>(
      Wu, Su, WuT, 4096ull * 1024, 4096, 1024, 8);
  tr_cvt2_kernel<<<dim3(16, 64, 9), 256, 0, stream>>>(
      Wd, Sd, WdT, 4096, 1024, 36864, 8);

  gemmUG3_kernel<<<2304, 512, 0, stream>>>(hb, WgT, WuT, T, gate, sgp);
  gemmD_kernel<<<256, 512, 0, stream>>>(T, WdT, P);
  reduce8_kernel<<<2048, 256, 0, stream>>>(P, out, 524288);
}